// Round 2
// baseline (49.805 us; speedup 1.0000x reference)
//
#include <hip/hip_runtime.h>

// Depthwise separable 4-tap blur, upfirdn2d pad=(2,1), weights [0.25,0.75,0.75,0.25]
// (symmetric -> conv flip is identity). LDS-free: horizontal via 16-lane shuffles,
// vertical via per-thread rolling register window.

#define PW 64
#define PH 64
#define CHUNK 16   // output rows per 16-lane group

__global__ __launch_bounds__(256) void blur_shfl_kernel(
    const float* __restrict__ x, float* __restrict__ out) {
    const int t = threadIdx.x;
    const int lane16 = t & 15;            // float4 column index within row
    const int grp = t >> 4;               // 16-lane group id, 0..15
    const int y0 = (grp >> 2) * CHUNK;    // wave-uniform chunk start: 0,16,32,48
    const int plane = blockIdx.x * 4 + (grp & 3);

    const float* __restrict__ src = x + (size_t)plane * (PH * PW) + lane16 * 4;
    float* __restrict__ dst = out + (size_t)plane * (PH * PW) + lane16 * 4;

    // rolling window of horizontally-filtered rows: hA=h[y-3], hB=h[y-2], hC=h[y-1]
    float4 hA = make_float4(0.f, 0.f, 0.f, 0.f);
    float4 hB = hA, hC = hA;

    #pragma unroll
    for (int i = 0; i < CHUNK + 3; ++i) {
        const int y = y0 - 2 + i;         // input row (wave-uniform)
        float4 v = make_float4(0.f, 0.f, 0.f, 0.f);
        if (y >= 0 && y < PH) {
            v = *reinterpret_cast<const float4*>(src + y * PW);
        }

        // ---- horizontal pass: pixels p=4*lane16 .. +3, taps {-2,-1,0,+1} ----
        float pz = __shfl_up(v.z, 1, 16);    // in[p-2] for component x
        float pw = __shfl_up(v.w, 1, 16);    // in[p-1] for component x
        float nx = __shfl_down(v.x, 1, 16);  // in[p+1] for component w
        if (lane16 == 0)  { pz = 0.f; pw = 0.f; }
        if (lane16 == 15) { nx = 0.f; }
        float4 hD;
        hD.x = 0.75f * (pw  + v.x) + 0.25f * (pz  + v.y);
        hD.y = 0.75f * (v.x + v.y) + 0.25f * (pw  + v.z);
        hD.z = 0.75f * (v.y + v.z) + 0.25f * (v.x + v.w);
        hD.w = 0.75f * (v.z + v.w) + 0.25f * (v.y + nx);

        // ---- vertical pass: out[y-1] = .25*h[y-3] + .75*h[y-2] + .75*h[y-1] + .25*h[y]
        if (i >= 3) {
            const int yo = y - 1;
            float4 o;
            o.x = 0.25f * (hA.x + hD.x) + 0.75f * (hB.x + hC.x);
            o.y = 0.25f * (hA.y + hD.y) + 0.75f * (hB.y + hC.y);
            o.z = 0.25f * (hA.z + hD.z) + 0.75f * (hB.z + hC.z);
            o.w = 0.25f * (hA.w + hD.w) + 0.75f * (hB.w + hC.w);
            *reinterpret_cast<float4*>(dst + yo * PW) = o;
        }
        hA = hB; hB = hC; hC = hD;
    }
}

extern "C" void kernel_launch(void* const* d_in, const int* in_sizes, int n_in,
                              void* d_out, int out_size, void* d_ws, size_t ws_size,
                              hipStream_t stream) {
    const float* x = (const float*)d_in[0];
    float* out = (float*)d_out;
    const int nplanes = in_sizes[0] / (PH * PW);   // 16*512 = 8192
    // 4 planes per block, 4 row-chunks per plane, 16 lanes per chunk-row
    blur_shfl_kernel<<<nplanes / 4, 256, 0, stream>>>(x, out);
}

// Round 5
// 44.078 us; speedup vs baseline: 1.1299x; 1.1299x over previous
//
#include <hip/hip_runtime.h>

// Depthwise separable 4-tap blur, upfirdn2d pad=(2,1), weights [0.25,0.75,0.75,0.25]
// (symmetric kernel -> conv flip is identity).
// One block per 64x64 plane. Horizontal pass fused into the load phase via
// 16-lane shuffles; h staged in LDS with zero-padded boundary rows; vertical
// pass is branch-free ds_read_b128 x4 + fma + float4 store. Single barrier.

#define PW 64
#define PH 64
#define LDW 68              // LDS row stride (floats): float4-aligned (68*4B=272B),
                            // row delta = 4 banks -> all accesses at 2-words/bank floor
#define ROWS (PH + 3)       // h[-2..64] stored at LDS rows 0..66

__global__ __launch_bounds__(256) void blur_fused_kernel(
    const float* __restrict__ x, float* __restrict__ out) {
    __shared__ float s_h[ROWS * LDW];

    const int t = threadIdx.x;
    const int plane = blockIdx.x;
    const float* __restrict__ src = x + (size_t)plane * (PH * PW);
    float* __restrict__ dst = out + (size_t)plane * (PH * PW);

    // ---- zero the 3 boundary rows: LDS rows 0,1 (h[-2],h[-1]) and 66 (h[64]) ----
    {
        const float4 z = make_float4(0.f, 0.f, 0.f, 0.f);
        if (t < 34)  // rows 0..1 = 136 floats = 34 float4
            reinterpret_cast<float4*>(&s_h[0])[t] = z;
        else if (t < 51)  // row 66 = 68 floats = 17 float4
            reinterpret_cast<float4*>(&s_h[(ROWS - 1) * LDW])[t - 34] = z;
    }

    const int lane16 = t & 15;

    // ---- Phase 1: load + horizontal pass -> LDS (rows shifted by +2) ----
    #pragma unroll
    for (int k = 0; k < 4; ++k) {
        const int f = t + k * 256;          // float4 index in plane
        const int y = f >> 4;               // source row
        const int x0 = (f & 15) << 2;       // first pixel of this float4
        const float4 v = reinterpret_cast<const float4*>(src)[f];

        float pz = __shfl_up(v.z, 1, 16);    // in[x0-2]
        float pw = __shfl_up(v.w, 1, 16);    // in[x0-1]
        float nx = __shfl_down(v.x, 1, 16);  // in[x0+4]
        if (lane16 == 0)  { pz = 0.f; pw = 0.f; }
        if (lane16 == 15) { nx = 0.f; }

        float4 h;
        h.x = 0.75f * (pw  + v.x) + 0.25f * (pz  + v.y);
        h.y = 0.75f * (v.x + v.y) + 0.25f * (pw  + v.z);
        h.z = 0.75f * (v.y + v.z) + 0.25f * (v.x + v.w);
        h.w = 0.75f * (v.z + v.w) + 0.25f * (v.y + nx);

        *reinterpret_cast<float4*>(&s_h[(y + 2) * LDW + x0]) = h;
    }
    __syncthreads();

    // ---- Phase 2: vertical pass, branch-free ----
    // out[y] = 0.25*(h[y-2]+h[y+1]) + 0.75*(h[y-1]+h[y]); h[y] lives at LDS row y+2
    #pragma unroll
    for (int k = 0; k < 4; ++k) {
        const int f = t + k * 256;
        const int y = f >> 4;
        const int x0 = (f & 15) << 2;
        const float* __restrict__ b = &s_h[y * LDW + x0];  // LDS row y = h[y-2]
        const float4 hA = *reinterpret_cast<const float4*>(b);
        const float4 hB = *reinterpret_cast<const float4*>(b + LDW);
        const float4 hC = *reinterpret_cast<const float4*>(b + 2 * LDW);
        const float4 hD = *reinterpret_cast<const float4*>(b + 3 * LDW);
        float4 o;
        o.x = 0.25f * (hA.x + hD.x) + 0.75f * (hB.x + hC.x);
        o.y = 0.25f * (hA.y + hD.y) + 0.75f * (hB.y + hC.y);
        o.z = 0.25f * (hA.z + hD.z) + 0.75f * (hB.z + hC.z);
        o.w = 0.25f * (hA.w + hD.w) + 0.75f * (hB.w + hC.w);
        reinterpret_cast<float4*>(dst)[f] = o;
    }
}

extern "C" void kernel_launch(void* const* d_in, const int* in_sizes, int n_in,
                              void* d_out, int out_size, void* d_ws, size_t ws_size,
                              hipStream_t stream) {
    const float* x = (const float*)d_in[0];
    float* out = (float*)d_out;
    const int nplanes = in_sizes[0] / (PH * PW);   // 16*512 = 8192
    blur_fused_kernel<<<nplanes, 256, 0, stream>>>(x, out);
}

// Round 6
// 43.929 us; speedup vs baseline: 1.1337x; 1.0034x over previous
//
#include <hip/hip_runtime.h>

// Depthwise separable 4-tap blur, upfirdn2d pad=(2,1), weights [0.25,0.75,0.75,0.25]
// (symmetric kernel -> conv flip is identity).
// One block per 64x64 plane. Horizontal pass fused into the load phase via
// 16-lane shuffles; h staged in LDS with zero-padded boundary rows; vertical
// pass is branch-free ds_read_b128 x4 + fma + nontemporal float4 store.
// NT stores keep the 134 MB input L3-resident across graph replays (output
// would otherwise evict it: 134+134 > 256 MB L3).

#define PW 64
#define PH 64
#define LDW 68              // LDS row stride (floats): float4-aligned (68*4B=272B)
#define ROWS (PH + 3)       // h[-2..64] stored at LDS rows 0..66

typedef float f4_t __attribute__((ext_vector_type(4)));

__global__ __launch_bounds__(256) void blur_fused_nt_kernel(
    const float* __restrict__ x, float* __restrict__ out) {
    __shared__ float s_h[ROWS * LDW];

    const int t = threadIdx.x;
    const int plane = blockIdx.x;
    const float* __restrict__ src = x + (size_t)plane * (PH * PW);
    float* __restrict__ dst = out + (size_t)plane * (PH * PW);

    // ---- zero the 3 boundary rows: LDS rows 0,1 (h[-2],h[-1]) and 66 (h[64]) ----
    {
        const float4 z = make_float4(0.f, 0.f, 0.f, 0.f);
        if (t < 34)  // rows 0..1 = 136 floats = 34 float4
            reinterpret_cast<float4*>(&s_h[0])[t] = z;
        else if (t < 51)  // row 66 = 68 floats = 17 float4
            reinterpret_cast<float4*>(&s_h[(ROWS - 1) * LDW])[t - 34] = z;
    }

    const int lane16 = t & 15;

    // ---- Phase 1: load + horizontal pass -> LDS (rows shifted by +2) ----
    #pragma unroll
    for (int k = 0; k < 4; ++k) {
        const int f = t + k * 256;          // float4 index in plane
        const int y = f >> 4;               // source row
        const int x0 = (f & 15) << 2;       // first pixel of this float4
        const float4 v = reinterpret_cast<const float4*>(src)[f];

        float pz = __shfl_up(v.z, 1, 16);    // in[x0-2]
        float pw = __shfl_up(v.w, 1, 16);    // in[x0-1]
        float nx = __shfl_down(v.x, 1, 16);  // in[x0+4]
        if (lane16 == 0)  { pz = 0.f; pw = 0.f; }
        if (lane16 == 15) { nx = 0.f; }

        float4 h;
        h.x = 0.75f * (pw  + v.x) + 0.25f * (pz  + v.y);
        h.y = 0.75f * (v.x + v.y) + 0.25f * (pw  + v.z);
        h.z = 0.75f * (v.y + v.z) + 0.25f * (v.x + v.w);
        h.w = 0.75f * (v.z + v.w) + 0.25f * (v.y + nx);

        *reinterpret_cast<float4*>(&s_h[(y + 2) * LDW + x0]) = h;
    }
    __syncthreads();

    // ---- Phase 2: vertical pass, branch-free, NT store ----
    // out[y] = 0.25*(h[y-2]+h[y+1]) + 0.75*(h[y-1]+h[y]); h[y] lives at LDS row y+2
    #pragma unroll
    for (int k = 0; k < 4; ++k) {
        const int f = t + k * 256;
        const int y = f >> 4;
        const int x0 = (f & 15) << 2;
        const float* __restrict__ b = &s_h[y * LDW + x0];  // LDS row y = h[y-2]
        const float4 hA = *reinterpret_cast<const float4*>(b);
        const float4 hB = *reinterpret_cast<const float4*>(b + LDW);
        const float4 hC = *reinterpret_cast<const float4*>(b + 2 * LDW);
        const float4 hD = *reinterpret_cast<const float4*>(b + 3 * LDW);
        f4_t o;
        o.x = 0.25f * (hA.x + hD.x) + 0.75f * (hB.x + hC.x);
        o.y = 0.25f * (hA.y + hD.y) + 0.75f * (hB.y + hC.y);
        o.z = 0.25f * (hA.z + hD.z) + 0.75f * (hB.z + hC.z);
        o.w = 0.25f * (hA.w + hD.w) + 0.75f * (hB.w + hC.w);
        __builtin_nontemporal_store(o, reinterpret_cast<f4_t*>(dst) + f);
    }
}

extern "C" void kernel_launch(void* const* d_in, const int* in_sizes, int n_in,
                              void* d_out, int out_size, void* d_ws, size_t ws_size,
                              hipStream_t stream) {
    const float* x = (const float*)d_in[0];
    float* out = (float*)d_out;
    const int nplanes = in_sizes[0] / (PH * PW);   // 16*512 = 8192
    blur_fused_nt_kernel<<<nplanes, 256, 0, stream>>>(x, out);
}